// Round 1
// baseline (7750.137 us; speedup 1.0000x reference)
//
#include <hip/hip_runtime.h>
#include <cstddef>

// Problem constants (fixed by setup_inputs)
#define B   4
#define D   512
#define T   2048
#define H   8
#define DH  64
#define NEG_SLOPE 0.2f
#define EPS 1e-6f
#define TM  4   // t-rows per attention block

// -----------------------------------------------------------------------------
// Kernel 1: leaky-ReLU + fused QKV projection
// h[n][b][hh][t][dd] = sum_d lrelu(x[b][d][t]) * qkv[n][hh][d][dd]
// One block computes a 64(t) x 64(dd) tile for one (b, g=n*8+hh).
// -----------------------------------------------------------------------------
__global__ __launch_bounds__(256) void qkv_proj(const float* __restrict__ x,
                                                const float* __restrict__ qkv,
                                                float* __restrict__ h) {
    const int t0 = blockIdx.x * 64;
    const int b  = blockIdx.y;
    const int g  = blockIdx.z;          // g = n*H + hh
    const int n  = g >> 3, hh = g & 7;

    __shared__ float As[32][64];        // [d][t], lrelu applied
    __shared__ float Ws[32][64];        // [d][dd]

    const int tid = threadIdx.x;
    const int ty = tid >> 4, tx = tid & 15;   // 16x16 threads, 4x4 micro-tile
    float acc[4][4] = {};

    const float* xb = x + (size_t)b * D * T;
    const float* wg = qkv + (size_t)g * D * DH;

    for (int k0 = 0; k0 < D; k0 += 32) {
        for (int l = 0; l < 8; ++l) {
            int e = l * 256 + tid;
            int r = e >> 6, c = e & 63;
            float xv = xb[(size_t)(k0 + r) * T + t0 + c];
            As[r][c] = xv >= 0.f ? xv : NEG_SLOPE * xv;
            Ws[r][c] = wg[(size_t)(k0 + r) * DH + c];
        }
        __syncthreads();
        for (int kk = 0; kk < 32; ++kk) {
            float a[4], w[4];
            for (int i = 0; i < 4; ++i) a[i] = As[kk][ty * 4 + i];
            for (int j = 0; j < 4; ++j) w[j] = Ws[kk][tx * 4 + j];
            for (int i = 0; i < 4; ++i)
                for (int j = 0; j < 4; ++j)
                    acc[i][j] += a[i] * w[j];
        }
        __syncthreads();
    }

    float* hb = h + (((size_t)n * B + b) * H + hh) * (size_t)T * DH;
    for (int i = 0; i < 4; ++i) {
        int t = t0 + ty * 4 + i;
        for (int j = 0; j < 4; ++j)
            hb[(size_t)t * DH + tx * 4 + j] = acc[i][j];
    }
}

// -----------------------------------------------------------------------------
// Kernel 2: RMSNorm over the T axis, in place.
// One block per (n,b,hh) slab of shape (T, DH).
// denom[dd] = mean_t h[t,dd]^2 ; h[t,dd] *= norm_w / sqrt(denom+EPS)
// -----------------------------------------------------------------------------
__global__ __launch_bounds__(256) void rmsnorm_t(float* __restrict__ h,
                                                 const float* __restrict__ norm_w) {
    float* hb = h + (size_t)blockIdx.x * T * DH;
    const int tid  = threadIdx.x;
    const int dd   = tid & 63;
    const int part = tid >> 6;

    float s = 0.f;
    for (int t = part; t < T; t += 4) {
        float v = hb[(size_t)t * DH + dd];
        s += v * v;
    }
    __shared__ float red[4][64];
    __shared__ float scale[64];
    red[part][dd] = s;
    __syncthreads();
    if (tid < 64) {
        float tot = red[0][tid] + red[1][tid] + red[2][tid] + red[3][tid];
        scale[tid] = norm_w[0] * rsqrtf(tot * (1.0f / T) + EPS);
    }
    __syncthreads();
    float sc = scale[dd];
    for (int t = part; t < T; t += 4)
        hb[(size_t)t * DH + dd] *= sc;
}

// -----------------------------------------------------------------------------
// Kernel 3: attention. One block per (b,hh, TM t-rows).
// Full score rows kept in LDS (TM x T), block softmax, then PV.
// out[b, hh*DH+dd, t] = sum_j softmax(q_t . k_j / 8)[j] * v[j,dd]
// -----------------------------------------------------------------------------
__global__ __launch_bounds__(256) void attn_kernel(const float* __restrict__ h,
                                                   float* __restrict__ out) {
    const int t0 = blockIdx.x * TM;
    const int bh = blockIdx.y;          // b*H + hh
    const int b  = bh >> 3, hh = bh & 7;
    const int tid = threadIdx.x;

    const size_t slab = (size_t)B * H * T * DH;
    const float* q  = h + (size_t)bh * T * DH;      // n=0
    const float* kp = q + slab;                     // n=1
    const float* vp = q + 2 * slab;                 // n=2

    __shared__ float qs[TM][DH];
    __shared__ float s[TM][T];          // 32 KB
    __shared__ float red[TM][256];      // 4 KB

    for (int e = tid; e < TM * DH; e += 256)
        qs[e / DH][e % DH] = q[(size_t)(t0 + e / DH) * DH + (e % DH)];
    __syncthreads();

    // ---- scores: each thread owns T/256 = 8 key rows, reuses each across TM q-rows
    for (int jj = 0; jj < T / 256; ++jj) {
        int j = jj * 256 + tid;
        const float4* krow = (const float4*)(kp + (size_t)j * DH);
        float dot[TM] = {};
        for (int c = 0; c < DH / 4; ++c) {
            float4 kv = krow[c];
            for (int r = 0; r < TM; ++r)
                dot[r] += qs[r][c * 4 + 0] * kv.x + qs[r][c * 4 + 1] * kv.y
                        + qs[r][c * 4 + 2] * kv.z + qs[r][c * 4 + 3] * kv.w;
        }
        for (int r = 0; r < TM; ++r) s[r][j] = dot[r] * 0.125f;  // /sqrt(64)
    }
    __syncthreads();

    // ---- per-row max
    float m[TM];
    for (int r = 0; r < TM; ++r) {
        float mm = -1e30f;
        for (int jj = 0; jj < T / 256; ++jj)
            mm = fmaxf(mm, s[r][jj * 256 + tid]);
        red[r][tid] = mm;
    }
    __syncthreads();
    for (int w = 128; w > 0; w >>= 1) {
        if (tid < w)
            for (int r = 0; r < TM; ++r)
                red[r][tid] = fmaxf(red[r][tid], red[r][tid + w]);
        __syncthreads();
    }
    for (int r = 0; r < TM; ++r) m[r] = red[r][0];
    __syncthreads();

    // ---- exp + sum
    float sums[TM] = {};
    for (int jj = 0; jj < T / 256; ++jj) {
        int j = jj * 256 + tid;
        for (int r = 0; r < TM; ++r) {
            float e = __expf(s[r][j] - m[r]);
            s[r][j] = e;
            sums[r] += e;
        }
    }
    for (int r = 0; r < TM; ++r) red[r][tid] = sums[r];
    __syncthreads();
    for (int w = 128; w > 0; w >>= 1) {
        if (tid < w)
            for (int r = 0; r < TM; ++r)
                red[r][tid] += red[r][tid + w];
        __syncthreads();
    }
    float inv_sum[TM];
    for (int r = 0; r < TM; ++r) inv_sum[r] = 1.f / red[r][0];
    __syncthreads();

    // ---- PV: thread (part,dd) sums a quarter of j-range for channel dd
    const int dd = tid & 63, part = tid >> 6;
    float acc[TM] = {};
    for (int j = part * (T / 4); j < (part + 1) * (T / 4); ++j) {
        float vval = vp[(size_t)j * DH + dd];
        for (int r = 0; r < TM; ++r) acc[r] += s[r][j] * vval;
    }
    for (int r = 0; r < TM; ++r) red[r][tid] = acc[r];
    __syncthreads();
    if (tid < 64) {
        for (int r = 0; r < TM; ++r) {
            float tot = red[r][tid] + red[r][64 + tid] + red[r][128 + tid] + red[r][192 + tid];
            out[((size_t)b * D + hh * DH + tid) * T + (t0 + r)] = tot * inv_sum[r];
        }
    }
}

// -----------------------------------------------------------------------------
extern "C" void kernel_launch(void* const* d_in, const int* in_sizes, int n_in,
                              void* d_out, int out_size, void* d_ws, size_t ws_size,
                              hipStream_t stream) {
    const float* x      = (const float*)d_in[0];
    const float* qkv    = (const float*)d_in[1];
    const float* norm_w = (const float*)d_in[2];
    float* out = (float*)d_out;
    float* h   = (float*)d_ws;   // 3*B*H*T*DH floats = 50.3 MB scratch

    qkv_proj<<<dim3(T / 64, B, 3 * H), 256, 0, stream>>>(x, qkv, h);
    rmsnorm_t<<<dim3(3 * B * H), 256, 0, stream>>>(h, norm_w);
    attn_kernel<<<dim3(T / TM, B * H), 256, 0, stream>>>(h, out);
}

// Round 2
// 370.831 us; speedup vs baseline: 20.8994x; 20.8994x over previous
//
#include <hip/hip_runtime.h>
#include <cstddef>

#define B   4
#define D   512
#define T   2048
#define H   8
#define DH  64
#define NEG_SLOPE 0.2f
#define EPS 1e-6f

typedef __attribute__((ext_vector_type(8))) short short8;   // 8 x bf16 (4 VGPRs)
typedef __attribute__((ext_vector_type(4))) float float4v;  // 4 x f32

__device__ __forceinline__ float bf2f(ushort u) {
    unsigned int x = ((unsigned int)u) << 16;
    return __builtin_bit_cast(float, x);
}
__device__ __forceinline__ ushort f2bf(float f) {
    unsigned int x = __builtin_bit_cast(unsigned int, f);
    x = x + 0x7fffu + ((x >> 16) & 1u);   // round-to-nearest-even
    return (ushort)(x >> 16);
}

// -----------------------------------------------------------------------------
// Kernel 1: leaky-ReLU + QKV projection -> bf16 h, plus per-channel sumsq.
// -----------------------------------------------------------------------------
__global__ __launch_bounds__(256) void qkv_proj(const float* __restrict__ x,
                                                const float* __restrict__ qkv,
                                                ushort* __restrict__ hb,
                                                float* __restrict__ ssq) {
    const int t0 = blockIdx.x * 64;
    const int b  = blockIdx.y;
    const int g  = blockIdx.z;          // g = n*H + hh
    const int n  = g >> 3, hh = g & 7;

    __shared__ float As[32][64];
    __shared__ float Ws[32][64];

    const int tid = threadIdx.x;
    const int ty = tid >> 4, tx = tid & 15;
    float acc[4][4] = {};

    const float* xb = x + (size_t)b * D * T;
    const float* wg = qkv + (size_t)g * D * DH;

    for (int k0 = 0; k0 < D; k0 += 32) {
        for (int l = 0; l < 8; ++l) {
            int e = l * 256 + tid;
            int r = e >> 6, c = e & 63;
            float xv = xb[(size_t)(k0 + r) * T + t0 + c];
            As[r][c] = xv >= 0.f ? xv : NEG_SLOPE * xv;
            Ws[r][c] = wg[(size_t)(k0 + r) * DH + c];
        }
        __syncthreads();
        #pragma unroll
        for (int kk = 0; kk < 32; ++kk) {
            float a[4], w[4];
            #pragma unroll
            for (int i = 0; i < 4; ++i) a[i] = As[kk][ty * 4 + i];
            #pragma unroll
            for (int j = 0; j < 4; ++j) w[j] = Ws[kk][tx * 4 + j];
            #pragma unroll
            for (int i = 0; i < 4; ++i)
                #pragma unroll
                for (int j = 0; j < 4; ++j)
                    acc[i][j] += a[i] * w[j];
        }
        __syncthreads();
    }

    // store bf16 h
    ushort* hbase = hb + (((size_t)n * B + b) * H + hh) * (size_t)T * DH;
    #pragma unroll
    for (int i = 0; i < 4; ++i) {
        int t = t0 + ty * 4 + i;
        ushort4 pk;
        pk.x = f2bf(acc[i][0]); pk.y = f2bf(acc[i][1]);
        pk.z = f2bf(acc[i][2]); pk.w = f2bf(acc[i][3]);
        *(ushort4*)(hbase + (size_t)t * DH + tx * 4) = pk;
    }

    // per-channel sum of squares (over this block's 64 t-rows), fp32
    float* red = &As[0][0];             // reuse 16x64 floats
    #pragma unroll
    for (int j = 0; j < 4; ++j) {
        float s = acc[0][j]*acc[0][j] + acc[1][j]*acc[1][j]
                + acc[2][j]*acc[2][j] + acc[3][j]*acc[3][j];
        red[ty * 64 + tx * 4 + j] = s;
    }
    __syncthreads();
    if (tid < 64) {
        float s = 0.f;
        #pragma unroll
        for (int yy = 0; yy < 16; ++yy) s += red[yy * 64 + tid];
        atomicAdd(&ssq[(((size_t)n * B + b) * H + hh) * 64 + tid], s);
    }
}

// -----------------------------------------------------------------------------
// Kernel 2: per-channel RMS scale
// -----------------------------------------------------------------------------
__global__ __launch_bounds__(256) void compute_scales(const float* __restrict__ ssq,
                                                      const float* __restrict__ norm_w,
                                                      float* __restrict__ scales) {
    int c = blockIdx.x * 256 + threadIdx.x;
    if (c < 3 * B * H * DH)
        scales[c] = norm_w[0] * rsqrtf(ssq[c] * (1.0f / T) + EPS);
}

// -----------------------------------------------------------------------------
// Kernel 3: flash attention, bf16 MFMA 16x16x32.
// Block: 256 thr = 4 waves; BM=128 q-rows (32/wave); BN=64 key tile.
// K tile is pre-scaled by sq*sk/8 at staging; V scale applied in epilogue.
// XOR-chunk swizzle on all LDS tiles -> conflict-free ds_read_b128 frags.
// -----------------------------------------------------------------------------
#define BM 128
#define BN 64

__global__ __launch_bounds__(256) void flash_attn(const ushort* __restrict__ hb,
                                                  const float* __restrict__ scales,
                                                  float* __restrict__ out) {
    const int tid  = threadIdx.x;
    const int wave = tid >> 6;
    const int lane = tid & 63;
    const int quad = lane >> 4;
    const int l16  = lane & 15;

    const int t0 = blockIdx.x * BM;
    const int bh = blockIdx.y;
    const int b  = bh >> 3, hh = bh & 7;

    const size_t slab = (size_t)B * H * T * DH;
    const ushort* qp = hb + (size_t)bh * T * DH;
    const ushort* kp = qp + slab;
    const ushort* vp = qp + 2 * slab;

    __shared__ ushort Kt[64 * 64];        // [n][chunk-swizzled dh]
    __shared__ ushort Vt[64 * 64];        // [dd][chunk-swizzled n]
    __shared__ ushort Pb[4][32 * 64];     // per-wave P [m][chunk-swizzled n]
    __shared__ float fqk[64], sv[64];

    if (tid < 64) {
        int cq = ((0 * B + b) * H + hh) * 64 + tid;
        int ck = ((1 * B + b) * H + hh) * 64 + tid;
        int cv = ((2 * B + b) * H + hh) * 64 + tid;
        fqk[tid] = scales[cq] * scales[ck] * 0.125f;   // includes 1/sqrt(Dh)
        sv[tid]  = scales[cv];
    }
    __syncthreads();

    // K-staging per-thread constants: this thread always loads chunk c of rows
    const int stg_c = tid & 7;            // dh-chunk 0..7
    const int stg_n = tid >> 3;           // row 0..31 (and +32 on 2nd pass)
    float ff[8];
    #pragma unroll
    for (int j = 0; j < 8; ++j) ff[j] = fqk[stg_c * 8 + j];

    // Q fragments (raw, unscaled): A[m=lane&15][k=quad*8+j]
    short8 aQ[2][2];
    const int qrow = t0 + wave * 32;
    #pragma unroll
    for (int mt = 0; mt < 2; ++mt)
        #pragma unroll
        for (int kh = 0; kh < 2; ++kh)
            aQ[mt][kh] = *(const short8*)(qp + (size_t)(qrow + mt * 16 + l16) * DH
                                             + kh * 32 + quad * 8);

    float m_run[2][4], l_run[2][4];
    float4v O[2][4];
    #pragma unroll
    for (int mt = 0; mt < 2; ++mt)
        #pragma unroll
        for (int r = 0; r < 4; ++r) { m_run[mt][r] = -1e30f; l_run[mt][r] = 0.f; }
    #pragma unroll
    for (int mt = 0; mt < 2; ++mt)
        #pragma unroll
        for (int dt = 0; dt < 4; ++dt) O[mt][dt] = (float4v){0.f, 0.f, 0.f, 0.f};

    for (int j0 = 0; j0 < T; j0 += BN) {
        // ---- stage K (scaled) : rows n, swizzled chunk = c ^ (n&7)
        #pragma unroll
        for (int it = 0; it < 2; ++it) {
            int n = stg_n + it * 32;
            uint4 raw = *(const uint4*)(kp + (size_t)(j0 + n) * DH + stg_c * 8);
            const ushort* rw = (const ushort*)&raw;
            ushort ov[8];
            #pragma unroll
            for (int j = 0; j < 8; ++j) ov[j] = f2bf(bf2f(rw[j]) * ff[j]);
            *(uint4*)&Kt[n * 64 + ((stg_c ^ (n & 7)) * 8)] = *(uint4*)ov;
        }
        // ---- stage V transposed: Vt[dd][n], swizzled chunk = c ^ (dd&7)
        {
            int dd = tid & 63, cc = tid >> 6;
            #pragma unroll
            for (int p = 0; p < 2; ++p) {
                int c = cc + p * 4;
                ushort vals[8];
                #pragma unroll
                for (int j = 0; j < 8; ++j)
                    vals[j] = vp[(size_t)(j0 + c * 8 + j) * DH + dd];
                *(uint4*)&Vt[dd * 64 + ((c ^ (dd & 7)) * 8)] = *(uint4*)vals;
            }
        }
        __syncthreads();

        // ---- S = Q * K^T (pre-scaled)
        float4v S[2][4];
        #pragma unroll
        for (int nt = 0; nt < 4; ++nt) {
            int row = nt * 16 + l16;
            short8 bK[2];
            #pragma unroll
            for (int kh = 0; kh < 2; ++kh)
                bK[kh] = *(const short8*)&Kt[row * 64 + (((kh * 4 + quad) ^ (row & 7)) * 8)];
            #pragma unroll
            for (int mt = 0; mt < 2; ++mt) {
                float4v c = {0.f, 0.f, 0.f, 0.f};
                c = __builtin_amdgcn_mfma_f32_16x16x32_bf16(aQ[mt][0], bK[0], c, 0, 0, 0);
                c = __builtin_amdgcn_mfma_f32_16x16x32_bf16(aQ[mt][1], bK[1], c, 0, 0, 0);
                S[mt][nt] = c;
            }
        }

        // ---- online softmax (row = mt*16 + quad*4 + r)
        #pragma unroll
        for (int mt = 0; mt < 2; ++mt) {
            #pragma unroll
            for (int r = 0; r < 4; ++r) {
                float mx = fmaxf(fmaxf(S[mt][0][r], S[mt][1][r]),
                                 fmaxf(S[mt][2][r], S[mt][3][r]));
                mx = fmaxf(mx, __shfl_xor(mx, 1));
                mx = fmaxf(mx, __shfl_xor(mx, 2));
                mx = fmaxf(mx, __shfl_xor(mx, 4));
                mx = fmaxf(mx, __shfl_xor(mx, 8));
                float mold = m_run[mt][r];
                float mnew = fmaxf(mold, mx);
                float alpha = __expf(mold - mnew);
                m_run[mt][r] = mnew;
                float rs = 0.f;
                int m = mt * 16 + quad * 4 + r;
                #pragma unroll
                for (int nt = 0; nt < 4; ++nt) {
                    float p = __expf(S[mt][nt][r] - mnew);
                    rs += p;
                    int nn = nt * 16 + l16;
                    Pb[wave][m * 64 + (((nn >> 3) ^ (m & 7)) * 8) + (nn & 7)] = f2bf(p);
                }
                rs += __shfl_xor(rs, 1);
                rs += __shfl_xor(rs, 2);
                rs += __shfl_xor(rs, 4);
                rs += __shfl_xor(rs, 8);
                l_run[mt][r] = l_run[mt][r] * alpha + rs;
                #pragma unroll
                for (int dt = 0; dt < 4; ++dt) O[mt][dt][r] *= alpha;
            }
        }

        // ---- O += P * V   (Pb is wave-private: no barrier needed)
        short8 aP[2][2];
        #pragma unroll
        for (int mt = 0; mt < 2; ++mt) {
            int am = mt * 16 + l16;
            #pragma unroll
            for (int nh = 0; nh < 2; ++nh)
                aP[mt][nh] = *(const short8*)&Pb[wave][am * 64 + (((nh * 4 + quad) ^ (am & 7)) * 8)];
        }
        #pragma unroll
        for (int dt = 0; dt < 4; ++dt) {
            int dd = dt * 16 + l16;
            short8 bV[2];
            #pragma unroll
            for (int nh = 0; nh < 2; ++nh)
                bV[nh] = *(const short8*)&Vt[dd * 64 + (((nh * 4 + quad) ^ (dd & 7)) * 8)];
            #pragma unroll
            for (int mt = 0; mt < 2; ++mt) {
                float4v c = O[mt][dt];
                c = __builtin_amdgcn_mfma_f32_16x16x32_bf16(aP[mt][0], bV[0], c, 0, 0, 0);
                c = __builtin_amdgcn_mfma_f32_16x16x32_bf16(aP[mt][1], bV[1], c, 0, 0, 0);
                O[mt][dt] = c;
            }
        }
        __syncthreads();   // protect Kt/Vt before next staging
    }

    // ---- epilogue: /l, *sv, store out[b, hh*64+dd, t]
    #pragma unroll
    for (int mt = 0; mt < 2; ++mt) {
        #pragma unroll
        for (int dt = 0; dt < 4; ++dt) {
            int dd = dt * 16 + l16;
            float s = sv[dd];
            #pragma unroll
            for (int r = 0; r < 4; ++r) {
                float v = O[mt][dt][r] * (1.f / l_run[mt][r]) * s;
                int t = t0 + wave * 32 + mt * 16 + quad * 4 + r;
                out[((size_t)b * D + hh * DH + dd) * T + t] = v;
            }
        }
    }
}

// -----------------------------------------------------------------------------
extern "C" void kernel_launch(void* const* d_in, const int* in_sizes, int n_in,
                              void* d_out, int out_size, void* d_ws, size_t ws_size,
                              hipStream_t stream) {
    const float* x      = (const float*)d_in[0];
    const float* qkv    = (const float*)d_in[1];
    const float* norm_w = (const float*)d_in[2];
    float* out = (float*)d_out;

    const size_t HB_BYTES = (size_t)3 * B * H * T * DH * 2;   // 25.2 MB bf16
    ushort* hb    = (ushort*)d_ws;
    float* ssq    = (float*)((char*)d_ws + HB_BYTES);
    float* scales = ssq + 3 * B * H * DH;

    hipMemsetAsync(ssq, 0, 3 * B * H * DH * sizeof(float), stream);
    qkv_proj<<<dim3(T / 64, B, 3 * H), 256, 0, stream>>>(x, qkv, hb, ssq);
    compute_scales<<<dim3((3 * B * H * DH + 255) / 256), 256, 0, stream>>>(ssq, norm_w, scales);
    flash_attn<<<dim3(T / BM, B * H), 256, 0, stream>>>(hb, scales, out);
}

// Round 3
// 226.969 us; speedup vs baseline: 34.1463x; 1.6338x over previous
//
#include <hip/hip_runtime.h>
#include <cstddef>

#define B   4
#define D   512
#define T   2048
#define H   8
#define DH  64
#define NEG_SLOPE 0.2f
#define EPS 1e-6f

typedef __attribute__((ext_vector_type(8))) short short8;   // 8 x bf16 (4 VGPRs)
typedef __attribute__((ext_vector_type(4))) float float4v;  // 4 x f32

__device__ __forceinline__ float bf2f(ushort u) {
    unsigned int x = ((unsigned int)u) << 16;
    return __builtin_bit_cast(float, x);
}
__device__ __forceinline__ ushort f2bf(float f) {
    unsigned int x = __builtin_bit_cast(unsigned int, f);
    x = x + 0x7fffu + ((x >> 16) & 1u);   // round-to-nearest-even
    return (ushort)(x >> 16);
}

// -----------------------------------------------------------------------------
// Kernel A: generic 64x64-tiled transpose fp32 -> bf16, optional leaky-ReLU.
// src: nmat matrices of (R x C), ld=src_ld. dst: (C x R), ld=dst_ld.
// grid = (C/64, R/64, nmat)
// -----------------------------------------------------------------------------
__global__ __launch_bounds__(256) void transpose_lrelu(const float* __restrict__ src,
                                                       ushort* __restrict__ dst,
                                                       int src_ld, int dst_ld,
                                                       size_t src_mstride, size_t dst_mstride,
                                                       int do_lrelu) {
    const int c0 = blockIdx.x * 64, r0 = blockIdx.y * 64;
    const float* s = src + blockIdx.z * src_mstride + (size_t)r0 * src_ld + c0;
    ushort*      d = dst + blockIdx.z * dst_mstride + (size_t)c0 * dst_ld + r0;

    __shared__ float Ls[64][68];   // pad 68 floats: 16B-aligned rows
    const int tid = threadIdx.x;

    // load: thread -> (row rl, 4 cols at c4)
    const int rl = tid >> 4, c4 = (tid & 15) * 4;
    #pragma unroll
    for (int p = 0; p < 4; ++p) {
        float4 v = *(const float4*)(s + (size_t)(rl + p * 16) * src_ld + c4);
        if (do_lrelu) {
            v.x = fmaxf(v.x, NEG_SLOPE * v.x);
            v.y = fmaxf(v.y, NEG_SLOPE * v.y);
            v.z = fmaxf(v.z, NEG_SLOPE * v.z);
            v.w = fmaxf(v.w, NEG_SLOPE * v.w);
        }
        *(float4*)&Ls[rl + p * 16][c4] = v;
    }
    __syncthreads();

    // store: thread -> (dst row tl = src col, chunk ch of 8 elems)
    const int tl = tid >> 2;
    #pragma unroll
    for (int it = 0; it < 2; ++it) {
        int ch = (tid & 3) + it * 4;
        ushort o[8];
        #pragma unroll
        for (int j = 0; j < 8; ++j) o[j] = f2bf(Ls[ch * 8 + j][tl]);
        *(uint4*)(d + (size_t)tl * dst_ld + ch * 8) = *(uint4*)o;
    }
}

// -----------------------------------------------------------------------------
// Kernel B: QKV GEMM via bf16 MFMA. C[b][t][gd] = sum_d xT[b][t][d] * WT[gd][d]
// Tile 128(t) x 128(gd), BK=64, 4 waves in 2x2, 64x64 per wave.
// global_load_lds width-16 staging, XOR-chunk swizzle (2-way conflicts only).
// Epilogue: bf16 h in flash layout + per-channel sumsq atomics.
// -----------------------------------------------------------------------------
__global__ __launch_bounds__(256) void qkv_mm(const ushort* __restrict__ xT,
                                              const ushort* __restrict__ WT,
                                              ushort* __restrict__ hb,
                                              float* __restrict__ ssq) {
    const int tid = threadIdx.x, wave = tid >> 6, lane = tid & 63;
    const int quad = lane >> 4, l16 = lane & 15;
    const int wr = wave >> 1, wc = wave & 1;
    const int t0  = blockIdx.x * 128;
    const int gd0 = blockIdx.y * 128;
    const int b   = blockIdx.z;

    __shared__ ushort At[128 * 64];   // [t-row][swizzled k-chunk]   16 KB
    __shared__ ushort Bt[128 * 64];   // [gd-row][swizzled k-chunk]  16 KB

    const ushort* xb = xT + (size_t)b * T * D + (size_t)t0 * D;
    const ushort* wb = WT + (size_t)gd0 * D;

    const int srow = lane >> 3;              // 0..7
    const int csrc = (lane & 7) ^ srow;      // source chunk for swizzled slot

    float4v acc[4][4];
    #pragma unroll
    for (int i = 0; i < 4; ++i)
        #pragma unroll
        for (int j = 0; j < 4; ++j) acc[i][j] = (float4v){0.f, 0.f, 0.f, 0.f};

    for (int k0 = 0; k0 < D; k0 += 64) {
        #pragma unroll
        for (int i = 0; i < 4; ++i) {
            int rbase = wave * 32 + i * 8;
            int row = rbase + srow;
            const ushort* ga = xb + (size_t)row * D + k0 + csrc * 8;
            const ushort* gb = wb + (size_t)row * D + k0 + csrc * 8;
            __builtin_amdgcn_global_load_lds(
                (const __attribute__((address_space(1))) unsigned int*)ga,
                (__attribute__((address_space(3))) unsigned int*)&At[rbase * 64], 16, 0, 0);
            __builtin_amdgcn_global_load_lds(
                (const __attribute__((address_space(1))) unsigned int*)gb,
                (__attribute__((address_space(3))) unsigned int*)&Bt[rbase * 64], 16, 0, 0);
        }
        __syncthreads();

        #pragma unroll
        for (int kh = 0; kh < 2; ++kh) {
            short8 aF[4], bF[4];
            #pragma unroll
            for (int mt = 0; mt < 4; ++mt) {
                int row = wr * 64 + mt * 16 + l16;
                aF[mt] = *(const short8*)&At[row * 64 + (((kh * 4 + quad) ^ (l16 & 7)) * 8)];
            }
            #pragma unroll
            for (int nt = 0; nt < 4; ++nt) {
                int row = wc * 64 + nt * 16 + l16;
                bF[nt] = *(const short8*)&Bt[row * 64 + (((kh * 4 + quad) ^ (l16 & 7)) * 8)];
            }
            #pragma unroll
            for (int mt = 0; mt < 4; ++mt)
                #pragma unroll
                for (int nt = 0; nt < 4; ++nt)
                    acc[mt][nt] = __builtin_amdgcn_mfma_f32_16x16x32_bf16(
                        aF[mt], bF[nt], acc[mt][nt], 0, 0, 0);
        }
        __syncthreads();
    }

    // epilogue: this wave's 64-col span is exactly one g
    const int g = blockIdx.y * 2 + wc;       // 0..23
    const int n = g >> 3, hh = g & 7;
    ushort* hbase = hb + (((size_t)n * B + b) * H + hh) * (size_t)T * DH;
    float colsq[4] = {0.f, 0.f, 0.f, 0.f};

    #pragma unroll
    for (int mt = 0; mt < 4; ++mt) {
        #pragma unroll
        for (int nt = 0; nt < 4; ++nt) {
            float4v c = acc[mt][nt];
            int dd = nt * 16 + l16;
            #pragma unroll
            for (int r = 0; r < 4; ++r) {
                int t = t0 + wr * 64 + mt * 16 + quad * 4 + r;
                hbase[(size_t)t * DH + dd] = f2bf(c[r]);
                colsq[nt] += c[r] * c[r];
            }
        }
    }
    #pragma unroll
    for (int nt = 0; nt < 4; ++nt) {
        float s = colsq[nt];
        s += __shfl_xor(s, 16);
        s += __shfl_xor(s, 32);
        if (quad == 0)
            atomicAdd(&ssq[(((size_t)n * B + b) * H + hh) * 64 + nt * 16 + l16], s);
    }
}

// -----------------------------------------------------------------------------
// Kernel C: per-channel RMS scale
// -----------------------------------------------------------------------------
__global__ __launch_bounds__(256) void compute_scales(const float* __restrict__ ssq,
                                                      const float* __restrict__ norm_w,
                                                      float* __restrict__ scales) {
    int c = blockIdx.x * 256 + threadIdx.x;
    if (c < 3 * B * H * DH)
        scales[c] = norm_w[0] * rsqrtf(ssq[c] * (1.0f / T) + EPS);
}

// -----------------------------------------------------------------------------
// Kernel D: flash attention, bf16 MFMA 16x16x32 (unchanged from round 2).
// -----------------------------------------------------------------------------
#define BM 128
#define BN 64

__global__ __launch_bounds__(256) void flash_attn(const ushort* __restrict__ hb,
                                                  const float* __restrict__ scales,
                                                  float* __restrict__ out) {
    const int tid  = threadIdx.x;
    const int wave = tid >> 6;
    const int lane = tid & 63;
    const int quad = lane >> 4;
    const int l16  = lane & 15;

    const int t0 = blockIdx.x * BM;
    const int bh = blockIdx.y;
    const int b  = bh >> 3, hh = bh & 7;

    const size_t slab = (size_t)B * H * T * DH;
    const ushort* qp = hb + (size_t)bh * T * DH;
    const ushort* kp = qp + slab;
    const ushort* vp = qp + 2 * slab;

    __shared__ ushort Kt[64 * 64];
    __shared__ ushort Vt[64 * 64];
    __shared__ ushort Pb[4][32 * 64];
    __shared__ float fqk[64], sv[64];

    if (tid < 64) {
        int cq = ((0 * B + b) * H + hh) * 64 + tid;
        int ck = ((1 * B + b) * H + hh) * 64 + tid;
        int cv = ((2 * B + b) * H + hh) * 64 + tid;
        fqk[tid] = scales[cq] * scales[ck] * 0.125f;
        sv[tid]  = scales[cv];
    }
    __syncthreads();

    const int stg_c = tid & 7;
    const int stg_n = tid >> 3;
    float ff[8];
    #pragma unroll
    for (int j = 0; j < 8; ++j) ff[j] = fqk[stg_c * 8 + j];

    short8 aQ[2][2];
    const int qrow = t0 + wave * 32;
    #pragma unroll
    for (int mt = 0; mt < 2; ++mt)
        #pragma unroll
        for (int kh = 0; kh < 2; ++kh)
            aQ[mt][kh] = *(const short8*)(qp + (size_t)(qrow + mt * 16 + l16) * DH
                                             + kh * 32 + quad * 8);

    float m_run[2][4], l_run[2][4];
    float4v O[2][4];
    #pragma unroll
    for (int mt = 0; mt < 2; ++mt)
        #pragma unroll
        for (int r = 0; r < 4; ++r) { m_run[mt][r] = -1e30f; l_run[mt][r] = 0.f; }
    #pragma unroll
    for (int mt = 0; mt < 2; ++mt)
        #pragma unroll
        for (int dt = 0; dt < 4; ++dt) O[mt][dt] = (float4v){0.f, 0.f, 0.f, 0.f};

    for (int j0 = 0; j0 < T; j0 += BN) {
        #pragma unroll
        for (int it = 0; it < 2; ++it) {
            int n = stg_n + it * 32;
            uint4 raw = *(const uint4*)(kp + (size_t)(j0 + n) * DH + stg_c * 8);
            const ushort* rw = (const ushort*)&raw;
            ushort ov[8];
            #pragma unroll
            for (int j = 0; j < 8; ++j) ov[j] = f2bf(bf2f(rw[j]) * ff[j]);
            *(uint4*)&Kt[n * 64 + ((stg_c ^ (n & 7)) * 8)] = *(uint4*)ov;
        }
        {
            int dd = tid & 63, cc = tid >> 6;
            #pragma unroll
            for (int p = 0; p < 2; ++p) {
                int c = cc + p * 4;
                ushort vals[8];
                #pragma unroll
                for (int j = 0; j < 8; ++j)
                    vals[j] = vp[(size_t)(j0 + c * 8 + j) * DH + dd];
                *(uint4*)&Vt[dd * 64 + ((c ^ (dd & 7)) * 8)] = *(uint4*)vals;
            }
        }
        __syncthreads();

        float4v S[2][4];
        #pragma unroll
        for (int nt = 0; nt < 4; ++nt) {
            int row = nt * 16 + l16;
            short8 bK[2];
            #pragma unroll
            for (int kh = 0; kh < 2; ++kh)
                bK[kh] = *(const short8*)&Kt[row * 64 + (((kh * 4 + quad) ^ (row & 7)) * 8)];
            #pragma unroll
            for (int mt = 0; mt < 2; ++mt) {
                float4v c = {0.f, 0.f, 0.f, 0.f};
                c = __builtin_amdgcn_mfma_f32_16x16x32_bf16(aQ[mt][0], bK[0], c, 0, 0, 0);
                c = __builtin_amdgcn_mfma_f32_16x16x32_bf16(aQ[mt][1], bK[1], c, 0, 0, 0);
                S[mt][nt] = c;
            }
        }

        #pragma unroll
        for (int mt = 0; mt < 2; ++mt) {
            #pragma unroll
            for (int r = 0; r < 4; ++r) {
                float mx = fmaxf(fmaxf(S[mt][0][r], S[mt][1][r]),
                                 fmaxf(S[mt][2][r], S[mt][3][r]));
                mx = fmaxf(mx, __shfl_xor(mx, 1));
                mx = fmaxf(mx, __shfl_xor(mx, 2));
                mx = fmaxf(mx, __shfl_xor(mx, 4));
                mx = fmaxf(mx, __shfl_xor(mx, 8));
                float mold = m_run[mt][r];
                float mnew = fmaxf(mold, mx);
                float alpha = __expf(mold - mnew);
                m_run[mt][r] = mnew;
                float rs = 0.f;
                int m = mt * 16 + quad * 4 + r;
                #pragma unroll
                for (int nt = 0; nt < 4; ++nt) {
                    float p = __expf(S[mt][nt][r] - mnew);
                    rs += p;
                    int nn = nt * 16 + l16;
                    Pb[wave][m * 64 + (((nn >> 3) ^ (m & 7)) * 8) + (nn & 7)] = f2bf(p);
                }
                rs += __shfl_xor(rs, 1);
                rs += __shfl_xor(rs, 2);
                rs += __shfl_xor(rs, 4);
                rs += __shfl_xor(rs, 8);
                l_run[mt][r] = l_run[mt][r] * alpha + rs;
                #pragma unroll
                for (int dt = 0; dt < 4; ++dt) O[mt][dt][r] *= alpha;
            }
        }

        short8 aP[2][2];
        #pragma unroll
        for (int mt = 0; mt < 2; ++mt) {
            int am = mt * 16 + l16;
            #pragma unroll
            for (int nh = 0; nh < 2; ++nh)
                aP[mt][nh] = *(const short8*)&Pb[wave][am * 64 + (((nh * 4 + quad) ^ (am & 7)) * 8)];
        }
        #pragma unroll
        for (int dt = 0; dt < 4; ++dt) {
            int dd = dt * 16 + l16;
            short8 bV[2];
            #pragma unroll
            for (int nh = 0; nh < 2; ++nh)
                bV[nh] = *(const short8*)&Vt[dd * 64 + (((nh * 4 + quad) ^ (dd & 7)) * 8)];
            #pragma unroll
            for (int mt = 0; mt < 2; ++mt) {
                float4v c = O[mt][dt];
                c = __builtin_amdgcn_mfma_f32_16x16x32_bf16(aP[mt][0], bV[0], c, 0, 0, 0);
                c = __builtin_amdgcn_mfma_f32_16x16x32_bf16(aP[mt][1], bV[1], c, 0, 0, 0);
                O[mt][dt] = c;
            }
        }
        __syncthreads();
    }

    #pragma unroll
    for (int mt = 0; mt < 2; ++mt) {
        #pragma unroll
        for (int dt = 0; dt < 4; ++dt) {
            int dd = dt * 16 + l16;
            float s = sv[dd];
            #pragma unroll
            for (int r = 0; r < 4; ++r) {
                float v = O[mt][dt][r] * (1.f / l_run[mt][r]) * s;
                int t = t0 + wave * 32 + mt * 16 + quad * 4 + r;
                out[((size_t)b * D + hh * DH + dd) * T + t] = v;
            }
        }
    }
}

// -----------------------------------------------------------------------------
extern "C" void kernel_launch(void* const* d_in, const int* in_sizes, int n_in,
                              void* d_out, int out_size, void* d_ws, size_t ws_size,
                              hipStream_t stream) {
    const float* x      = (const float*)d_in[0];
    const float* qkv    = (const float*)d_in[1];
    const float* norm_w = (const float*)d_in[2];
    float* out = (float*)d_out;

    const size_t HB_BYTES = (size_t)3 * B * H * T * DH * 2;   // 25.17 MB
    const size_t XT_BYTES = (size_t)B * T * D * 2;            //  8.39 MB
    const size_t WT_BYTES = (size_t)3 * H * DH * D * 2;       //  1.57 MB
    ushort* hb    = (ushort*)d_ws;
    ushort* xT    = (ushort*)((char*)d_ws + HB_BYTES);
    ushort* WT    = (ushort*)((char*)d_ws + HB_BYTES + XT_BYTES);
    float*  ssq   = (float*)((char*)d_ws + HB_BYTES + XT_BYTES + WT_BYTES);
    float*  scales = ssq + 3 * B * H * DH;

    // x[b]: (D x T) -> xT[b]: (T x D), with leaky-ReLU
    transpose_lrelu<<<dim3(T / 64, D / 64, B), 256, 0, stream>>>(
        x, xT, T, D, (size_t)D * T, (size_t)T * D, 1);
    // qkv[g]: (D x DH) -> WT[g]: (DH x D)
    transpose_lrelu<<<dim3(DH / 64, D / 64, 3 * H), 256, 0, stream>>>(
        qkv, WT, DH, D, (size_t)D * DH, (size_t)DH * D, 0);

    hipMemsetAsync(ssq, 0, 3 * B * H * DH * sizeof(float), stream);
    qkv_mm<<<dim3(T / 128, (3 * H * DH) / 128, B), 256, 0, stream>>>(xT, WT, hb, ssq);
    compute_scales<<<dim3((3 * B * H * DH + 255) / 256), 256, 0, stream>>>(ssq, norm_w, scales);
    flash_attn<<<dim3(T / BM, B * H), 256, 0, stream>>>(hb, scales, out);
}

// Round 4
// 176.053 us; speedup vs baseline: 44.0217x; 1.2892x over previous
//
#include <hip/hip_runtime.h>
#include <cstddef>

#define B   4
#define D   512
#define T   2048
#define H   8
#define DH  64
#define NEG_SLOPE 0.2f
#define EPS 1e-6f

typedef __attribute__((ext_vector_type(8))) short short8;   // 8 x bf16 (4 VGPRs)
typedef __attribute__((ext_vector_type(4))) float float4v;  // 4 x f32

__device__ __forceinline__ float bf2f(ushort u) {
    unsigned int x = ((unsigned int)u) << 16;
    return __builtin_bit_cast(float, x);
}
__device__ __forceinline__ ushort f2bf(float f) {
    unsigned int x = __builtin_bit_cast(unsigned int, f);
    x = x + 0x7fffu + ((x >> 16) & 1u);   // round-to-nearest-even
    return (ushort)(x >> 16);
}

// -----------------------------------------------------------------------------
// Kernel A: 64x64-tiled transpose fp32 -> bf16, optional leaky-ReLU.
// -----------------------------------------------------------------------------
__global__ __launch_bounds__(256) void transpose_lrelu(const float* __restrict__ src,
                                                       ushort* __restrict__ dst,
                                                       int src_ld, int dst_ld,
                                                       size_t src_mstride, size_t dst_mstride,
                                                       int do_lrelu) {
    const int c0 = blockIdx.x * 64, r0 = blockIdx.y * 64;
    const float* s = src + blockIdx.z * src_mstride + (size_t)r0 * src_ld + c0;
    ushort*      d = dst + blockIdx.z * dst_mstride + (size_t)c0 * dst_ld + r0;

    __shared__ float Ls[64][68];
    const int tid = threadIdx.x;

    const int rl = tid >> 4, c4 = (tid & 15) * 4;
    #pragma unroll
    for (int p = 0; p < 4; ++p) {
        float4 v = *(const float4*)(s + (size_t)(rl + p * 16) * src_ld + c4);
        if (do_lrelu) {
            v.x = fmaxf(v.x, NEG_SLOPE * v.x);
            v.y = fmaxf(v.y, NEG_SLOPE * v.y);
            v.z = fmaxf(v.z, NEG_SLOPE * v.z);
            v.w = fmaxf(v.w, NEG_SLOPE * v.w);
        }
        *(float4*)&Ls[rl + p * 16][c4] = v;
    }
    __syncthreads();

    const int tl = tid >> 2;
    #pragma unroll
    for (int it = 0; it < 2; ++it) {
        int ch = (tid & 3) + it * 4;
        ushort o[8];
        #pragma unroll
        for (int j = 0; j < 8; ++j) o[j] = f2bf(Ls[ch * 8 + j][tl]);
        *(uint4*)(d + (size_t)tl * dst_ld + ch * 8) = *(uint4*)o;
    }
}

// -----------------------------------------------------------------------------
// Kernel B: QKV GEMM via bf16 MFMA. C[b][t][gd] = sum_d xT[b][t][d] * WT[gd][d]
// Q/K heads -> hb[t][dh] layout; V heads -> vT[dd][t] (transposed) layout.
// Also accumulates per-channel sumsq for RMSNorm.
// -----------------------------------------------------------------------------
__global__ __launch_bounds__(256) void qkv_mm(const ushort* __restrict__ xT,
                                              const ushort* __restrict__ WT,
                                              ushort* __restrict__ hb,
                                              ushort* __restrict__ vT,
                                              float* __restrict__ ssq) {
    const int tid = threadIdx.x, wave = tid >> 6, lane = tid & 63;
    const int quad = lane >> 4, l16 = lane & 15;
    const int wr = wave >> 1, wc = wave & 1;
    const int t0  = blockIdx.x * 128;
    const int gd0 = blockIdx.y * 128;
    const int b   = blockIdx.z;

    __shared__ ushort At[128 * 64];
    __shared__ ushort Bt[128 * 64];

    const ushort* xb = xT + (size_t)b * T * D + (size_t)t0 * D;
    const ushort* wb = WT + (size_t)gd0 * D;

    const int srow = lane >> 3;
    const int csrc = (lane & 7) ^ srow;

    float4v acc[4][4];
    #pragma unroll
    for (int i = 0; i < 4; ++i)
        #pragma unroll
        for (int j = 0; j < 4; ++j) acc[i][j] = (float4v){0.f, 0.f, 0.f, 0.f};

    for (int k0 = 0; k0 < D; k0 += 64) {
        #pragma unroll
        for (int i = 0; i < 4; ++i) {
            int rbase = wave * 32 + i * 8;
            int row = rbase + srow;
            const ushort* ga = xb + (size_t)row * D + k0 + csrc * 8;
            const ushort* gb = wb + (size_t)row * D + k0 + csrc * 8;
            __builtin_amdgcn_global_load_lds(
                (const __attribute__((address_space(1))) unsigned int*)ga,
                (__attribute__((address_space(3))) unsigned int*)&At[rbase * 64], 16, 0, 0);
            __builtin_amdgcn_global_load_lds(
                (const __attribute__((address_space(1))) unsigned int*)gb,
                (__attribute__((address_space(3))) unsigned int*)&Bt[rbase * 64], 16, 0, 0);
        }
        __syncthreads();

        #pragma unroll
        for (int kh = 0; kh < 2; ++kh) {
            short8 aF[4], bF[4];
            #pragma unroll
            for (int mt = 0; mt < 4; ++mt) {
                int row = wr * 64 + mt * 16 + l16;
                aF[mt] = *(const short8*)&At[row * 64 + (((kh * 4 + quad) ^ (l16 & 7)) * 8)];
            }
            #pragma unroll
            for (int nt = 0; nt < 4; ++nt) {
                int row = wc * 64 + nt * 16 + l16;
                bF[nt] = *(const short8*)&Bt[row * 64 + (((kh * 4 + quad) ^ (l16 & 7)) * 8)];
            }
            #pragma unroll
            for (int mt = 0; mt < 4; ++mt)
                #pragma unroll
                for (int nt = 0; nt < 4; ++nt)
                    acc[mt][nt] = __builtin_amdgcn_mfma_f32_16x16x32_bf16(
                        aF[mt], bF[nt], acc[mt][nt], 0, 0, 0);
        }
        __syncthreads();
    }

    const int g = blockIdx.y * 2 + wc;       // 0..23
    const int n = g >> 3, hh = g & 7;
    float colsq[4] = {0.f, 0.f, 0.f, 0.f};

    if (n < 2) {
        // Q/K heads: row-major hb[t][dh]
        ushort* hbase = hb + (((size_t)n * B + b) * H + hh) * (size_t)T * DH;
        #pragma unroll
        for (int mt = 0; mt < 4; ++mt) {
            #pragma unroll
            for (int nt = 0; nt < 4; ++nt) {
                float4v c = acc[mt][nt];
                int dd = nt * 16 + l16;
                #pragma unroll
                for (int r = 0; r < 4; ++r) {
                    int t = t0 + wr * 64 + mt * 16 + quad * 4 + r;
                    hbase[(size_t)t * DH + dd] = f2bf(c[r]);
                    colsq[nt] += c[r] * c[r];
                }
            }
        }
    } else {
        // V heads: transposed vT[dd][t]
        ushort* vbase = vT + ((size_t)b * H + hh) * (size_t)DH * T;
        #pragma unroll
        for (int mt = 0; mt < 4; ++mt) {
            #pragma unroll
            for (int nt = 0; nt < 4; ++nt) {
                float4v c = acc[mt][nt];
                int dd = nt * 16 + l16;
                int t  = t0 + wr * 64 + mt * 16 + quad * 4;
                ushort4 pk;
                pk.x = f2bf(c[0]); pk.y = f2bf(c[1]);
                pk.z = f2bf(c[2]); pk.w = f2bf(c[3]);
                *(ushort4*)(vbase + (size_t)dd * T + t) = pk;
                colsq[nt] += c[0]*c[0] + c[1]*c[1] + c[2]*c[2] + c[3]*c[3];
            }
        }
    }
    #pragma unroll
    for (int nt = 0; nt < 4; ++nt) {
        float s = colsq[nt];
        s += __shfl_xor(s, 16);
        s += __shfl_xor(s, 32);
        if (quad == 0)
            atomicAdd(&ssq[(((size_t)n * B + b) * H + hh) * 64 + nt * 16 + l16], s);
    }
}

// -----------------------------------------------------------------------------
// Kernel C: per-channel RMS scale
// -----------------------------------------------------------------------------
__global__ __launch_bounds__(256) void compute_scales(const float* __restrict__ ssq,
                                                      const float* __restrict__ norm_w,
                                                      float* __restrict__ scales) {
    int c = blockIdx.x * 256 + threadIdx.x;
    if (c < 3 * B * H * DH)
        scales[c] = norm_w[0] * rsqrtf(ssq[c] * (1.0f / T) + EPS);
}

// -----------------------------------------------------------------------------
// Kernel D: flash attention, S^T = K*Q^T formulation.
// Block = 4 waves, 64 queries (16/wave, query index = lane&15).
// Keys live in MFMA C-registers -> softmax is in-register + 2 shuffles.
// K staged raw (scale folded into Q regs), V^T staged raw, both via
// global_load_lds with XOR-chunk swizzle. P^T roundtrip: 4 ds_write_b64 +
// 2 ds_read_b128 per wave per tile (wave-private buffer, no barrier).
// blockIdx remapped so each head's 32 t-tiles land on one XCD (L2 locality).
// -----------------------------------------------------------------------------
__global__ __launch_bounds__(256, 4) void flash_attn(const ushort* __restrict__ hb,
                                                     const ushort* __restrict__ vT,
                                                     const float* __restrict__ scales,
                                                     float* __restrict__ out) {
    const int tid  = threadIdx.x;
    const int wave = tid >> 6;
    const int lane = tid & 63;
    const int quad = lane >> 4;
    const int l16  = lane & 15;

    // XCD-locality remap: head = f(lin%32) constant per XCD, ttile = lin/32
    const int lin  = blockIdx.x;
    const int head = ((lin & 7) << 2) | ((lin >> 3) & 3);   // b*H+hh
    const int t0   = (lin >> 5) * 64;
    const int b    = head >> 3, hh = head & 7;

    const size_t slab = (size_t)B * H * T * DH;
    const ushort* qp = hb + (size_t)head * T * DH;
    const ushort* kp = hb + slab + (size_t)head * T * DH;
    const ushort* vp = vT + (size_t)head * DH * T;

    __shared__ ushort Kt[64 * 64];        // [key][swizzled dh-chunk]  8 KB
    __shared__ ushort Vt[64 * 64];        // [dd][swizzled key-chunk]  8 KB
    __shared__ ushort Pb[4][16 * 64];     // per-wave P^T-ish [query][swizzled key-chunk]
    __shared__ float fqk[64], sv[64];

    if (tid < 64) {
        float sq = scales[(0 * B * H + head) * 64 + tid];
        float sk = scales[(1 * B * H + head) * 64 + tid];
        fqk[tid] = sq * sk * 0.125f;      // 1/sqrt(Dh) folded
        sv[tid]  = scales[(2 * B * H + head) * 64 + tid];
    }
    __syncthreads();

    // ---- Q B-frags (col = query = l16), pre-scaled by fqk
    short8 bQ[2];
    {
        const ushort* qr = qp + (size_t)(t0 + wave * 16 + l16) * DH;
        #pragma unroll
        for (int kh = 0; kh < 2; ++kh) {
            short8 raw = *(const short8*)(qr + kh * 32 + quad * 8);
            #pragma unroll
            for (int j = 0; j < 8; ++j) {
                float f = bf2f((ushort)raw[j]) * fqk[kh * 32 + quad * 8 + j];
                bQ[kh][j] = (short)f2bf(f);
            }
        }
    }

    // ---- staging lane constants (8 rows x 8 chunks per issue)
    const int srow = lane >> 3;
    const int csrc = (lane & 7) ^ srow;          // XOR-chunk swizzle source
    const ushort* kA = kp + (size_t)(wave * 16 + srow) * DH + csrc * 8;
    const ushort* kB = kp + (size_t)(wave * 16 + 8 + srow) * DH + csrc * 8;
    const ushort* vA = vp + (size_t)(wave * 16 + srow) * T + csrc * 8;
    const ushort* vB = vp + (size_t)(wave * 16 + 8 + srow) * T + csrc * 8;

    float m_run = -1e30f, l_run = 0.f;
    float4v O[4];
    #pragma unroll
    for (int dt = 0; dt < 4; ++dt) O[dt] = (float4v){0.f, 0.f, 0.f, 0.f};

    for (int j0 = 0; j0 < T; j0 += 64) {
        // ---- stage K (raw) and V^T (raw), async direct-to-LDS
        __builtin_amdgcn_global_load_lds(
            (const __attribute__((address_space(1))) unsigned int*)(kA + (size_t)j0 * DH),
            (__attribute__((address_space(3))) unsigned int*)&Kt[(wave * 16) * 64], 16, 0, 0);
        __builtin_amdgcn_global_load_lds(
            (const __attribute__((address_space(1))) unsigned int*)(kB + (size_t)j0 * DH),
            (__attribute__((address_space(3))) unsigned int*)&Kt[(wave * 16 + 8) * 64], 16, 0, 0);
        __builtin_amdgcn_global_load_lds(
            (const __attribute__((address_space(1))) unsigned int*)(vA + j0),
            (__attribute__((address_space(3))) unsigned int*)&Vt[(wave * 16) * 64], 16, 0, 0);
        __builtin_amdgcn_global_load_lds(
            (const __attribute__((address_space(1))) unsigned int*)(vB + j0),
            (__attribute__((address_space(3))) unsigned int*)&Vt[(wave * 16 + 8) * 64], 16, 0, 0);
        __syncthreads();

        // ---- S^T = K * Q^T : C col = query(l16), rows = keys (regs)
        float4v S[4];
        #pragma unroll
        for (int mt = 0; mt < 4; ++mt) S[mt] = (float4v){0.f, 0.f, 0.f, 0.f};
        #pragma unroll
        for (int kh = 0; kh < 2; ++kh) {
            #pragma unroll
            for (int mt = 0; mt < 4; ++mt) {
                int row = mt * 16 + l16;
                short8 aK = *(const short8*)&Kt[row * 64 + (((kh * 4 + quad) ^ (l16 & 7)) * 8)];
                S[mt] = __builtin_amdgcn_mfma_f32_16x16x32_bf16(aK, bQ[kh], S[mt], 0, 0, 0);
            }
        }

        // ---- online softmax for this lane's query (16 scores in regs)
        float mx = fmaxf(fmaxf(fmaxf(S[0][0], S[0][1]), fmaxf(S[0][2], S[0][3])),
                         fmaxf(fmaxf(S[1][0], S[1][1]), fmaxf(S[1][2], S[1][3])));
        mx = fmaxf(mx, fmaxf(fmaxf(fmaxf(S[2][0], S[2][1]), fmaxf(S[2][2], S[2][3])),
                             fmaxf(fmaxf(S[3][0], S[3][1]), fmaxf(S[3][2], S[3][3]))));
        mx = fmaxf(mx, __shfl_xor(mx, 16));
        mx = fmaxf(mx, __shfl_xor(mx, 32));
        float mnew  = fmaxf(m_run, mx);
        float alpha = __expf(m_run - mnew);
        m_run = mnew;

        float rs = 0.f;
        #pragma unroll
        for (int mt = 0; mt < 4; ++mt) {
            ushort pk[4];
            #pragma unroll
            for (int r = 0; r < 4; ++r) {
                float p = __expf(S[mt][r] - mnew);
                rs += p;
                pk[r] = f2bf(p);
            }
            // key = mt*16 + quad*4 + r ; chunk = mt*2+(quad>>1), off = (quad&1)*4
            *(ushort4*)&Pb[wave][l16 * 64 + (((mt * 2 + (quad >> 1)) ^ (l16 & 7)) * 8)
                                + (quad & 1) * 4] = *(ushort4*)pk;
        }
        rs += __shfl_xor(rs, 16);
        rs += __shfl_xor(rs, 32);
        l_run = l_run * alpha + rs;
        #pragma unroll
        for (int dt = 0; dt < 4; ++dt) {
            O[dt][0] *= alpha; O[dt][1] *= alpha;
            O[dt][2] *= alpha; O[dt][3] *= alpha;
        }

        // ---- O^T += V^T * P^T (wave-private Pb: no barrier needed)
        #pragma unroll
        for (int kh = 0; kh < 2; ++kh) {
            short8 bP = *(const short8*)&Pb[wave][l16 * 64 + (((kh * 4 + quad) ^ (l16 & 7)) * 8)];
            #pragma unroll
            for (int dt = 0; dt < 4; ++dt) {
                int row = dt * 16 + l16;
                short8 aV = *(const short8*)&Vt[row * 64 + (((kh * 4 + quad) ^ (row & 7)) * 8)];
                O[dt] = __builtin_amdgcn_mfma_f32_16x16x32_bf16(aV, bP, O[dt], 0, 0, 0);
            }
        }
        __syncthreads();   // protect Kt/Vt before next staging
    }

    // ---- epilogue: lane's query column t, rows dd = dt*16+quad*4+r
    float inv = 1.f / l_run;
    const int t = t0 + wave * 16 + l16;
    #pragma unroll
    for (int dt = 0; dt < 4; ++dt) {
        #pragma unroll
        for (int r = 0; r < 4; ++r) {
            int dd = dt * 16 + quad * 4 + r;
            out[((size_t)b * D + hh * DH + dd) * T + t] = O[dt][r] * inv * sv[dd];
        }
    }
}

// -----------------------------------------------------------------------------
extern "C" void kernel_launch(void* const* d_in, const int* in_sizes, int n_in,
                              void* d_out, int out_size, void* d_ws, size_t ws_size,
                              hipStream_t stream) {
    const float* x      = (const float*)d_in[0];
    const float* qkv    = (const float*)d_in[1];
    const float* norm_w = (const float*)d_in[2];
    float* out = (float*)d_out;

    const size_t HB_BYTES = (size_t)2 * B * H * T * DH * 2;   // Q+K slabs, 16.8 MB
    const size_t VT_BYTES = (size_t)B * H * DH * T * 2;       //  8.4 MB
    const size_t XT_BYTES = (size_t)B * T * D * 2;            //  8.4 MB
    const size_t WT_BYTES = (size_t)3 * H * DH * D * 2;       //  1.6 MB
    ushort* hb     = (ushort*)d_ws;
    ushort* vT     = (ushort*)((char*)d_ws + HB_BYTES);
    ushort* xT     = (ushort*)((char*)d_ws + HB_BYTES + VT_BYTES);
    ushort* WT     = (ushort*)((char*)d_ws + HB_BYTES + VT_BYTES + XT_BYTES);
    float*  ssq    = (float*)((char*)d_ws + HB_BYTES + VT_BYTES + XT_BYTES + WT_BYTES);
    float*  scales = ssq + 3 * B * H * DH;

    transpose_lrelu<<<dim3(T / 64, D / 64, B), 256, 0, stream>>>(
        x, xT, T, D, (size_t)D * T, (size_t)T * D, 1);
    transpose_lrelu<<<dim3(DH / 64, D / 64, 3 * H), 256, 0, stream>>>(
        qkv, WT, DH, D, (size_t)D * DH, (size_t)DH * D, 0);

    hipMemsetAsync(ssq, 0, 3 * B * H * DH * sizeof(float), stream);
    qkv_mm<<<dim3(T / 128, (3 * H * DH) / 128, B), 256, 0, stream>>>(xT, WT, hb, vT, ssq);
    compute_scales<<<dim3((3 * B * H * DH + 255) / 256), 256, 0, stream>>>(ssq, norm_w, scales);
    flash_attn<<<dim3((T / 64) * B * H), 256, 0, stream>>>(hb, vT, scales, out);
}

// Round 5
// 154.889 us; speedup vs baseline: 50.0368x; 1.1366x over previous
//
#include <hip/hip_runtime.h>
#include <cstddef>

#define B   4
#define D   512
#define T   2048
#define H   8
#define DH  64
#define NEG_SLOPE 0.2f
#define EPS 1e-6f
#define LOG2E 1.44269504088896340736f

typedef __attribute__((ext_vector_type(8))) short short8;   // 8 x bf16 (4 VGPRs)
typedef __attribute__((ext_vector_type(4))) float float4v;  // 4 x f32

__device__ __forceinline__ float bf2f(ushort u) {
    unsigned int x = ((unsigned int)u) << 16;
    return __builtin_bit_cast(float, x);
}
__device__ __forceinline__ ushort f2bf(float f) {
    unsigned int x = __builtin_bit_cast(unsigned int, f);
    x = x + 0x7fffu + ((x >> 16) & 1u);   // round-to-nearest-even
    return (ushort)(x >> 16);
}

// -----------------------------------------------------------------------------
// Kernel A: 64x64-tiled transpose fp32 -> bf16, optional leaky-ReLU.
// Block (0,0,0) also zeroes zbuf (ssq accumulator) when zbuf != nullptr.
// -----------------------------------------------------------------------------
__global__ __launch_bounds__(256) void transpose_lrelu(const float* __restrict__ src,
                                                       ushort* __restrict__ dst,
                                                       int src_ld, int dst_ld,
                                                       size_t src_mstride, size_t dst_mstride,
                                                       int do_lrelu,
                                                       float* __restrict__ zbuf, int zcount) {
    const int tid = threadIdx.x;
    if (zbuf != nullptr && blockIdx.x == 0 && blockIdx.y == 0 && blockIdx.z == 0) {
        for (int i = tid; i < zcount; i += 256) zbuf[i] = 0.f;
    }

    const int c0 = blockIdx.x * 64, r0 = blockIdx.y * 64;
    const float* s = src + blockIdx.z * src_mstride + (size_t)r0 * src_ld + c0;
    ushort*      d = dst + blockIdx.z * dst_mstride + (size_t)c0 * dst_ld + r0;

    __shared__ float Ls[64][68];

    const int rl = tid >> 4, c4 = (tid & 15) * 4;
    #pragma unroll
    for (int p = 0; p < 4; ++p) {
        float4 v = *(const float4*)(s + (size_t)(rl + p * 16) * src_ld + c4);
        if (do_lrelu) {
            v.x = fmaxf(v.x, NEG_SLOPE * v.x);
            v.y = fmaxf(v.y, NEG_SLOPE * v.y);
            v.z = fmaxf(v.z, NEG_SLOPE * v.z);
            v.w = fmaxf(v.w, NEG_SLOPE * v.w);
        }
        *(float4*)&Ls[rl + p * 16][c4] = v;
    }
    __syncthreads();

    const int tl = tid >> 2;
    #pragma unroll
    for (int it = 0; it < 2; ++it) {
        int ch = (tid & 3) + it * 4;
        ushort o[8];
        #pragma unroll
        for (int j = 0; j < 8; ++j) o[j] = f2bf(Ls[ch * 8 + j][tl]);
        *(uint4*)(d + (size_t)tl * dst_ld + ch * 8) = *(uint4*)o;
    }
}

// -----------------------------------------------------------------------------
// Kernel B: QKV GEMM via bf16 MFMA. C[b][t][gd] = sum_d xT[b][t][d] * WT[gd][d]
// Q/K heads -> hb[t][dh]; V heads -> vT[dd][t]. Accumulates per-channel sumsq.
// -----------------------------------------------------------------------------
__global__ __launch_bounds__(256) void qkv_mm(const ushort* __restrict__ xT,
                                              const ushort* __restrict__ WT,
                                              ushort* __restrict__ hb,
                                              ushort* __restrict__ vT,
                                              float* __restrict__ ssq) {
    const int tid = threadIdx.x, wave = tid >> 6, lane = tid & 63;
    const int quad = lane >> 4, l16 = lane & 15;
    const int wr = wave >> 1, wc = wave & 1;
    const int t0  = blockIdx.x * 128;
    const int gd0 = blockIdx.y * 128;
    const int b   = blockIdx.z;

    __shared__ ushort At[128 * 64];
    __shared__ ushort Bt[128 * 64];

    const ushort* xb = xT + (size_t)b * T * D + (size_t)t0 * D;
    const ushort* wb = WT + (size_t)gd0 * D;

    const int srow = lane >> 3;
    const int csrc = (lane & 7) ^ srow;

    float4v acc[4][4];
    #pragma unroll
    for (int i = 0; i < 4; ++i)
        #pragma unroll
        for (int j = 0; j < 4; ++j) acc[i][j] = (float4v){0.f, 0.f, 0.f, 0.f};

    for (int k0 = 0; k0 < D; k0 += 64) {
        #pragma unroll
        for (int i = 0; i < 4; ++i) {
            int rbase = wave * 32 + i * 8;
            int row = rbase + srow;
            const ushort* ga = xb + (size_t)row * D + k0 + csrc * 8;
            const ushort* gb = wb + (size_t)row * D + k0 + csrc * 8;
            __builtin_amdgcn_global_load_lds(
                (const __attribute__((address_space(1))) unsigned int*)ga,
                (__attribute__((address_space(3))) unsigned int*)&At[rbase * 64], 16, 0, 0);
            __builtin_amdgcn_global_load_lds(
                (const __attribute__((address_space(1))) unsigned int*)gb,
                (__attribute__((address_space(3))) unsigned int*)&Bt[rbase * 64], 16, 0, 0);
        }
        __syncthreads();

        #pragma unroll
        for (int kh = 0; kh < 2; ++kh) {
            short8 aF[4], bF[4];
            #pragma unroll
            for (int mt = 0; mt < 4; ++mt) {
                int row = wr * 64 + mt * 16 + l16;
                aF[mt] = *(const short8*)&At[row * 64 + (((kh * 4 + quad) ^ (l16 & 7)) * 8)];
            }
            #pragma unroll
            for (int nt = 0; nt < 4; ++nt) {
                int row = wc * 64 + nt * 16 + l16;
                bF[nt] = *(const short8*)&Bt[row * 64 + (((kh * 4 + quad) ^ (l16 & 7)) * 8)];
            }
            #pragma unroll
            for (int mt = 0; mt < 4; ++mt)
                #pragma unroll
                for (int nt = 0; nt < 4; ++nt)
                    acc[mt][nt] = __builtin_amdgcn_mfma_f32_16x16x32_bf16(
                        aF[mt], bF[nt], acc[mt][nt], 0, 0, 0);
        }
        __syncthreads();
    }

    const int g = blockIdx.y * 2 + wc;       // 0..23
    const int n = g >> 3, hh = g & 7;
    float colsq[4] = {0.f, 0.f, 0.f, 0.f};

    if (n < 2) {
        ushort* hbase = hb + (((size_t)n * B + b) * H + hh) * (size_t)T * DH;
        #pragma unroll
        for (int mt = 0; mt < 4; ++mt) {
            #pragma unroll
            for (int nt = 0; nt < 4; ++nt) {
                float4v c = acc[mt][nt];
                int dd = nt * 16 + l16;
                #pragma unroll
                for (int r = 0; r < 4; ++r) {
                    int t = t0 + wr * 64 + mt * 16 + quad * 4 + r;
                    hbase[(size_t)t * DH + dd] = f2bf(c[r]);
                    colsq[nt] += c[r] * c[r];
                }
            }
        }
    } else {
        ushort* vbase = vT + ((size_t)b * H + hh) * (size_t)DH * T;
        #pragma unroll
        for (int mt = 0; mt < 4; ++mt) {
            #pragma unroll
            for (int nt = 0; nt < 4; ++nt) {
                float4v c = acc[mt][nt];
                int dd = nt * 16 + l16;
                int t  = t0 + wr * 64 + mt * 16 + quad * 4;
                ushort4 pk;
                pk.x = f2bf(c[0]); pk.y = f2bf(c[1]);
                pk.z = f2bf(c[2]); pk.w = f2bf(c[3]);
                *(ushort4*)(vbase + (size_t)dd * T + t) = pk;
                colsq[nt] += c[0]*c[0] + c[1]*c[1] + c[2]*c[2] + c[3]*c[3];
            }
        }
    }
    #pragma unroll
    for (int nt = 0; nt < 4; ++nt) {
        float s = colsq[nt];
        s += __shfl_xor(s, 16);
        s += __shfl_xor(s, 32);
        if (quad == 0)
            atomicAdd(&ssq[(((size_t)n * B + b) * H + hh) * 64 + nt * 16 + l16], s);
    }
}

// -----------------------------------------------------------------------------
// Kernel C: flash attention, S^T = K*Q^T, NO online max (scores ~N(0,1):
// exp2 cannot overflow fp32/bf16 exponent range). log2e folded into Q scale.
// l-reduction deferred to epilogue (2 shuffles total). P packed via v_perm.
// RMS scales computed inline from ssq (compute_scales kernel fused away).
// -----------------------------------------------------------------------------
__global__ __launch_bounds__(256, 4) void flash_attn(const ushort* __restrict__ hb,
                                                     const ushort* __restrict__ vT,
                                                     const float* __restrict__ ssq,
                                                     const float* __restrict__ norm_w,
                                                     float* __restrict__ out) {
    const int tid  = threadIdx.x;
    const int wave = tid >> 6;
    const int lane = tid & 63;
    const int quad = lane >> 4;
    const int l16  = lane & 15;

    // XCD-locality remap: all 32 t-tiles of a head land on one XCD
    const int lin  = blockIdx.x;
    const int head = ((lin & 7) << 2) | ((lin >> 3) & 3);   // b*H+hh
    const int t0   = (lin >> 5) * 64;
    const int b    = head >> 3, hh = head & 7;

    const size_t slab = (size_t)B * H * T * DH;
    const ushort* qp = hb + (size_t)head * T * DH;
    const ushort* kp = hb + slab + (size_t)head * T * DH;
    const ushort* vp = vT + (size_t)head * DH * T;

    __shared__ ushort Kt[64 * 64];        // 8 KB
    __shared__ ushort Vt[64 * 64];        // 8 KB
    __shared__ ushort Pb[4][16 * 64];     // 8 KB, wave-private quadrants
    __shared__ float fqk[64], sv[64];

    if (tid < 64) {
        float nw = norm_w[0];
        float mq = ssq[(0 * B * H + head) * 64 + tid] * (1.0f / T) + EPS;
        float mk = ssq[(1 * B * H + head) * 64 + tid] * (1.0f / T) + EPS;
        float mv = ssq[(2 * B * H + head) * 64 + tid] * (1.0f / T) + EPS;
        fqk[tid] = nw * nw * rsqrtf(mq) * rsqrtf(mk) * 0.125f * LOG2E;
        sv[tid]  = nw * rsqrtf(mv);
    }
    __syncthreads();

    // ---- Q B-frags (col = query = l16), pre-scaled by fqk (incl. log2e)
    short8 bQ[2];
    {
        const ushort* qr = qp + (size_t)(t0 + wave * 16 + l16) * DH;
        #pragma unroll
        for (int kh = 0; kh < 2; ++kh) {
            short8 raw = *(const short8*)(qr + kh * 32 + quad * 8);
            #pragma unroll
            for (int j = 0; j < 8; ++j) {
                float f = bf2f((ushort)raw[j]) * fqk[kh * 32 + quad * 8 + j];
                bQ[kh][j] = (short)f2bf(f);
            }
        }
    }

    // ---- staging lane constants
    const int srow = lane >> 3;
    const int csrc = (lane & 7) ^ srow;
    const ushort* kA = kp + (size_t)(wave * 16 + srow) * DH + csrc * 8;
    const ushort* kB = kp + (size_t)(wave * 16 + 8 + srow) * DH + csrc * 8;
    const ushort* vA = vp + (size_t)(wave * 16 + srow) * T + csrc * 8;
    const ushort* vB = vp + (size_t)(wave * 16 + 8 + srow) * T + csrc * 8;

    float l_run = 0.f;
    float4v O[4];
    #pragma unroll
    for (int dt = 0; dt < 4; ++dt) O[dt] = (float4v){0.f, 0.f, 0.f, 0.f};

    for (int j0 = 0; j0 < T; j0 += 64) {
        __builtin_amdgcn_global_load_lds(
            (const __attribute__((address_space(1))) unsigned int*)(kA + (size_t)j0 * DH),
            (__attribute__((address_space(3))) unsigned int*)&Kt[(wave * 16) * 64], 16, 0, 0);
        __builtin_amdgcn_global_load_lds(
            (const __attribute__((address_space(1))) unsigned int*)(kB + (size_t)j0 * DH),
            (__attribute__((address_space(3))) unsigned int*)&Kt[(wave * 16 + 8) * 64], 16, 0, 0);
        __builtin_amdgcn_global_load_lds(
            (const __attribute__((address_space(1))) unsigned int*)(vA + j0),
            (__attribute__((address_space(3))) unsigned int*)&Vt[(wave * 16) * 64], 16, 0, 0);
        __builtin_amdgcn_global_load_lds(
            (const __attribute__((address_space(1))) unsigned int*)(vB + j0),
            (__attribute__((address_space(3))) unsigned int*)&Vt[(wave * 16 + 8) * 64], 16, 0, 0);
        __syncthreads();

        // ---- S^T = K * Q^T (already in log2 domain)
        float4v S[4];
        #pragma unroll
        for (int mt = 0; mt < 4; ++mt) S[mt] = (float4v){0.f, 0.f, 0.f, 0.f};
        #pragma unroll
        for (int kh = 0; kh < 2; ++kh) {
            #pragma unroll
            for (int mt = 0; mt < 4; ++mt) {
                int row = mt * 16 + l16;
                short8 aK = *(const short8*)&Kt[row * 64 + (((kh * 4 + quad) ^ (l16 & 7)) * 8)];
                S[mt] = __builtin_amdgcn_mfma_f32_16x16x32_bf16(aK, bQ[kh], S[mt], 0, 0, 0);
            }
        }

        // ---- P = exp2(S), accumulate partial l, pack to bf16 via v_perm
        #pragma unroll
        for (int mt = 0; mt < 4; ++mt) {
            float p0 = __builtin_amdgcn_exp2f(S[mt][0]);
            float p1 = __builtin_amdgcn_exp2f(S[mt][1]);
            float p2 = __builtin_amdgcn_exp2f(S[mt][2]);
            float p3 = __builtin_amdgcn_exp2f(S[mt][3]);
            l_run += (p0 + p1) + (p2 + p3);
            unsigned int a0 = __builtin_bit_cast(unsigned int, p0) + 0x8000u;
            unsigned int a1 = __builtin_bit_cast(unsigned int, p1) + 0x8000u;
            unsigned int a2 = __builtin_bit_cast(unsigned int, p2) + 0x8000u;
            unsigned int a3 = __builtin_bit_cast(unsigned int, p3) + 0x8000u;
            uint2 pk;
            pk.x = __builtin_amdgcn_perm(a1, a0, 0x07060302u);
            pk.y = __builtin_amdgcn_perm(a3, a2, 0x07060302u);
            *(uint2*)&Pb[wave][l16 * 64 + (((mt * 2 + (quad >> 1)) ^ (l16 & 7)) * 8)
                               + (quad & 1) * 4] = pk;
        }

        // ---- O^T += V^T * P^T (Pb wave-private: no barrier)
        #pragma unroll
        for (int kh = 0; kh < 2; ++kh) {
            short8 bP = *(const short8*)&Pb[wave][l16 * 64 + (((kh * 4 + quad) ^ (l16 & 7)) * 8)];
            #pragma unroll
            for (int dt = 0; dt < 4; ++dt) {
                int row = dt * 16 + l16;
                short8 aV = *(const short8*)&Vt[row * 64 + (((kh * 4 + quad) ^ (row & 7)) * 8)];
                O[dt] = __builtin_amdgcn_mfma_f32_16x16x32_bf16(aV, bP, O[dt], 0, 0, 0);
            }
        }
        __syncthreads();
    }

    // ---- epilogue: cross-quad l reduction (once), then store
    float rs = l_run;
    rs += __shfl_xor(rs, 16);
    rs += __shfl_xor(rs, 32);
    float inv = 1.f / rs;
    const int t = t0 + wave * 16 + l16;
    #pragma unroll
    for (int dt = 0; dt < 4; ++dt) {
        #pragma unroll
        for (int r = 0; r < 4; ++r) {
            int dd = dt * 16 + quad * 4 + r;
            out[((size_t)b * D + hh * DH + dd) * T + t] = O[dt][r] * inv * sv[dd];
        }
    }
}

// -----------------------------------------------------------------------------
extern "C" void kernel_launch(void* const* d_in, const int* in_sizes, int n_in,
                              void* d_out, int out_size, void* d_ws, size_t ws_size,
                              hipStream_t stream) {
    const float* x      = (const float*)d_in[0];
    const float* qkv    = (const float*)d_in[1];
    const float* norm_w = (const float*)d_in[2];
    float* out = (float*)d_out;

    const size_t HB_BYTES = (size_t)2 * B * H * T * DH * 2;   // Q+K slabs
    const size_t VT_BYTES = (size_t)B * H * DH * T * 2;
    const size_t XT_BYTES = (size_t)B * T * D * 2;
    const size_t WT_BYTES = (size_t)3 * H * DH * D * 2;
    ushort* hb  = (ushort*)d_ws;
    ushort* vT  = (ushort*)((char*)d_ws + HB_BYTES);
    ushort* xT  = (ushort*)((char*)d_ws + HB_BYTES + VT_BYTES);
    ushort* WT  = (ushort*)((char*)d_ws + HB_BYTES + VT_BYTES + XT_BYTES);
    float*  ssq = (float*)((char*)d_ws + HB_BYTES + VT_BYTES + XT_BYTES + WT_BYTES);
    const int SSQ_N = 3 * B * H * DH;

    // x transpose also zeroes ssq (block 0) — it strictly precedes qkv_mm.
    transpose_lrelu<<<dim3(T / 64, D / 64, B), 256, 0, stream>>>(
        x, xT, T, D, (size_t)D * T, (size_t)T * D, 1, ssq, SSQ_N);
    transpose_lrelu<<<dim3(DH / 64, D / 64, 3 * H), 256, 0, stream>>>(
        qkv, WT, DH, D, (size_t)D * DH, (size_t)DH * D, 0, nullptr, 0);

    qkv_mm<<<dim3(T / 128, (3 * H * DH) / 128, B), 256, 0, stream>>>(xT, WT, hb, vT, ssq);
    flash_attn<<<dim3((T / 64) * B * H), 256, 0, stream>>>(hb, vT, ssq, norm_w, out);
}